// Round 5
// baseline (1163.871 us; speedup 1.0000x reference)
//
#include <hip/hip_runtime.h>

#define NEGS 0.2f

__device__ __forceinline__ float lrelu(float x){ return x > 0.f ? x : NEGS*x; }
__device__ __forceinline__ float sel4(float4 v, int h){
    float lo = (h & 1) ? v.y : v.x;
    float hi = (h & 1) ? v.w : v.z;
    return (h & 2) ? hi : lo;
}

// ---------------- W transpose (tiny, once per launch) ----------------
__global__ __launch_bounds__(256) void k_transpose(const float* __restrict__ Wsrc,
        const float* __restrict__ Wres, float* __restrict__ WTs, float* __restrict__ WTr){
    int t = blockIdx.x*256 + threadIdx.x;  // 0..16383
    if (t < 16384){
        int j = t >> 7, k = t & 127;       // coalesced read over k
        WTs[k*128 + j] = Wsrc[t];
        WTr[k*128 + j] = Wres[t];
    }
}

// ---------------- GEMM: xp = feats@Wsrc^T, res(d_out) = feats@Wres^T ----------------
__global__ __launch_bounds__(256) void k_gemm(const float* __restrict__ feats,
        const float* __restrict__ WTs, const float* __restrict__ WTr,
        float* __restrict__ xp, float* __restrict__ res, int n){
    __shared__ float fs[64][128];
    int t = threadIdx.x;
    int n0 = blockIdx.x * 64;
    const float4* f4 = (const float4*)feats;
    #pragma unroll
    for (int i = 0; i < 8; ++i){
        int idx = t + i*256;               // 2048 float4 units
        int row = idx >> 5, c4 = idx & 31;
        float4 v = make_float4(0.f,0.f,0.f,0.f);
        if (n0 + row < n) v = f4[(size_t)(n0+row)*32 + c4];
        fs[row][c4*4+0]=v.x; fs[row][c4*4+1]=v.y; fs[row][c4*4+2]=v.z; fs[row][c4*4+3]=v.w;
    }
    __syncthreads();
    int tn = t >> 5;          // 8 node groups
    int tc = t & 31;          // 32 col groups
    int j0 = tc*4;
    float acc[8][4], acr[8][4];
    #pragma unroll
    for(int i=0;i<8;++i){
        #pragma unroll
        for(int c=0;c<4;++c){ acc[i][c]=0.f; acr[i][c]=0.f; }
    }
    #pragma unroll 4
    for (int k=0;k<128;++k){
        float4 wv = *(const float4*)(WTs + k*128 + j0);
        float4 rv = *(const float4*)(WTr + k*128 + j0);
        #pragma unroll
        for (int i=0;i<8;++i){
            float f = fs[tn*8+i][k];
            acc[i][0]+=f*wv.x; acc[i][1]+=f*wv.y; acc[i][2]+=f*wv.z; acc[i][3]+=f*wv.w;
            acr[i][0]+=f*rv.x; acr[i][1]+=f*rv.y; acr[i][2]+=f*rv.z; acr[i][3]+=f*rv.w;
        }
    }
    #pragma unroll
    for(int i=0;i<8;++i){
        int nn = n0 + tn*8 + i;
        if (nn < n){
            *(float4*)(xp  + (size_t)nn*128 + j0) = make_float4(acc[i][0],acc[i][1],acc[i][2],acc[i][3]);
            *(float4*)(res + (size_t)nn*128 + j0) = make_float4(acr[i][0],acr[i][1],acr[i][2],acr[i][3]);
        }
    }
}

// ---------------- attention scalar per node: a = sum_c xp[n,h,c]*att[h,c] ----------------
__global__ __launch_bounds__(256) void k_attn(const float* __restrict__ xp,
        const float* __restrict__ att_s, const float* __restrict__ att_d,
        float* __restrict__ a_src, float* __restrict__ a_dst, int n){
    int w = threadIdx.x >> 6, lane = threadIdx.x & 63;
    int node = blockIdx.x*4 + w;
    if (node >= n) return;
    float x0 = xp[(size_t)node*128 + lane];
    float x1 = xp[(size_t)node*128 + 64 + lane];
    float s0 = x0 * att_s[lane],    s1 = x1 * att_s[64+lane];
    float d0 = x0 * att_d[lane],    d1 = x1 * att_d[64+lane];
    #pragma unroll
    for (int off=16; off; off>>=1){
        s0 += __shfl_xor(s0, off); s1 += __shfl_xor(s1, off);
        d0 += __shfl_xor(d0, off); d1 += __shfl_xor(d1, off);
    }
    if ((lane & 31) == 0){
        int h = lane >> 5;  // 0 or 1
        a_src[node*4 + h]     = s0;
        a_src[node*4 + 2 + h] = s1;
        a_dst[node*4 + h]     = d0;
        a_dst[node*4 + 2 + h] = d1;
    }
}

// ---------------- CSR build ----------------
__global__ void k_deg(const int* __restrict__ ei, int* __restrict__ deg, int e){
    int i = blockIdx.x*blockDim.x + threadIdx.x;
    if (i < e) atomicAdd(&deg[ei[e + i]], 1);
}

__global__ __launch_bounds__(256) void k_bsum(const int* __restrict__ deg, int* __restrict__ bsum, int n){
    __shared__ int sm[256];
    int i = blockIdx.x*256 + threadIdx.x;
    sm[threadIdx.x] = (i<n)? deg[i] : 0;
    __syncthreads();
    for (int s=128; s; s>>=1){ if ((int)threadIdx.x < s) sm[threadIdx.x]+=sm[threadIdx.x+s]; __syncthreads(); }
    if (!threadIdx.x) bsum[blockIdx.x] = sm[0];
}

__global__ void k_bscan(const int* __restrict__ bsum, int* __restrict__ boff, int nb){
    if (threadIdx.x==0 && blockIdx.x==0){
        int run=0;
        for (int b=0;b<nb;++b){ boff[b]=run; run+=bsum[b]; }
    }
}

__global__ __launch_bounds__(256) void k_scan(const int* __restrict__ deg, const int* __restrict__ boff,
        int* __restrict__ offs, int n){
    __shared__ int sm[256];
    int i = blockIdx.x*256 + threadIdx.x;
    int v = (i<n)? deg[i]:0;
    sm[threadIdx.x]=v;
    __syncthreads();
    for (int s=1;s<256;s<<=1){
        int add = ((int)threadIdx.x>=s)? sm[threadIdx.x-s]:0;
        __syncthreads();
        sm[threadIdx.x]+=add;
        __syncthreads();
    }
    int excl = sm[threadIdx.x]-v;
    if (i<=n) offs[i]=boff[blockIdx.x]+excl;
}

__global__ void k_scatter(const int* __restrict__ ei, const int* __restrict__ offs,
        int* __restrict__ cursor, int* __restrict__ nbr, int e){
    int i = blockIdx.x*blockDim.x + threadIdx.x;
    if (i<e){
        int s = ei[i], d = ei[e+i];
        int pos = atomicAdd(&cursor[d],1);
        nbr[offs[d]+pos] = s;
    }
}

// ---------------- fused softmax + aggregation + residual + BN partials ----------------
// One wave per node. Chunk = 16 edges. All gathers are UNCONDITIONAL (OOB slots
// clamped to `node`, whose row is L1-hot) so the 8 row-pair loads can issue as one
// clustered burst and stay in flight together. __launch_bounds__(256,4) gives the
// register allocator a 128-VGPR budget so xv[8] stays live (round-4's 44 VGPRs
// forced issue-wait-reuse serialization => 1 outstanding miss/wave).
__global__ __launch_bounds__(256, 4) void k_aggr(const float* __restrict__ xp,
        const float* __restrict__ a_src, const float* __restrict__ a_dst,
        const int* __restrict__ offs, const int* __restrict__ nbr,
        const float* __restrict__ bias, float* __restrict__ out,
        float* __restrict__ gsum, float* __restrict__ gsq, int n){
    __shared__ float lsum[4][128];
    __shared__ float lsq[4][128];
    int w = threadIdx.x >> 6, lane = threadIdx.x & 63;
    int c32 = lane & 31;        // float4 slot within 128-ch row
    int e2  = lane >> 5;        // which edge of each pair
    int h   = c32 >> 3;         // head (C=32 -> 8 float4 per head)
    int node = blockIdx.x*4 + w;
    const float4* a4  = (const float4*)a_src;
    const float4* xp4 = (const float4*)xp;
    float4 o = make_float4(0.f,0.f,0.f,0.f);
    if (node < n){
        float4 ad4 = *(const float4*)(a_dst + node*4);
        float adh = sel4(ad4, h);
        int beg = offs[node];
        int deg = offs[node+1] - beg;
        float4 acc = make_float4(0.f,0.f,0.f,0.f);
        float ssum = 0.f;
        // self loop on half e2==0
        {
            float4 as4 = a4[node];
            float ws = __expf(lrelu(sel4(as4, h) + adh));
            float4 xs = xp4[(size_t)node*32 + c32];
            if (e2 == 0){
                ssum = ws;
                acc.x = ws*xs.x; acc.y = ws*xs.y; acc.z = ws*xs.z; acc.w = ws*xs.w;
            }
        }
        for (int ch0 = 0; ch0 < deg; ch0 += 16){
            int cnt = min(16, deg - ch0);
            // holder lanes (0..15) fetch neighbor ids; others clamp to node
            int sidv = node;
            if (lane < cnt) sidv = nbr[beg + ch0 + lane];
            float4 av = a4[sidv];                     // unconditional gather
            float4 w4;
            w4.x = __expf(lrelu(av.x + ad4.x));
            w4.y = __expf(lrelu(av.y + ad4.y));
            w4.z = __expf(lrelu(av.z + ad4.z));
            w4.w = __expf(lrelu(av.w + ad4.w));
            // gather my 8 edge ids up front (clamped), then burst-load 8 rows
            int  sid[8];
            bool ok[8];
            #pragma unroll
            for (int p = 0; p < 8; ++p){
                int j = p*2 + e2;
                int s = __shfl(sidv, j);
                ok[p]  = (j < cnt);
                sid[p] = ok[p] ? s : node;
            }
            float4 xv[8];
            #pragma unroll
            for (int p = 0; p < 8; ++p){
                xv[p] = xp4[(size_t)sid[p]*32 + c32];   // 8 independent loads in flight
            }
            // distribute weights and accumulate
            #pragma unroll
            for (int p = 0; p < 8; ++p){
                int j = p*2 + e2;
                float4 wv;
                wv.x = __shfl(w4.x, j); wv.y = __shfl(w4.y, j);
                wv.z = __shfl(w4.z, j); wv.w = __shfl(w4.w, j);
                float wgt = ok[p] ? sel4(wv, h) : 0.f;
                ssum += wgt;
                acc.x += wgt*xv[p].x; acc.y += wgt*xv[p].y;
                acc.z += wgt*xv[p].z; acc.w += wgt*xv[p].w;
            }
        }
        // combine the two edge-halves
        acc.x += __shfl_xor(acc.x, 32); acc.y += __shfl_xor(acc.y, 32);
        acc.z += __shfl_xor(acc.z, 32); acc.w += __shfl_xor(acc.w, 32);
        ssum  += __shfl_xor(ssum, 32);
        float inv = 1.f/(ssum + 1e-16f);
        if (e2 == 0){
            float4 r = *(const float4*)(out + (size_t)node*128 + c32*4);
            float4 b = *(const float4*)(bias + c32*4);
            o.x = acc.x*inv + r.x + b.x; o.y = acc.y*inv + r.y + b.y;
            o.z = acc.z*inv + r.z + b.z; o.w = acc.w*inv + r.w + b.w;
            *(float4*)(out + (size_t)node*128 + c32*4) = o;
        }
    }
    if (e2 == 0){
        *(float4*)&lsum[w][c32*4] = o;
        float4 q = make_float4(o.x*o.x, o.y*o.y, o.z*o.z, o.w*o.w);
        *(float4*)&lsq[w][c32*4]  = q;
    }
    __syncthreads();
    int t = threadIdx.x;
    if (t < 128){
        float s = lsum[0][t]+lsum[1][t]+lsum[2][t]+lsum[3][t];
        atomicAdd(&gsum[t], s);
    } else {
        int c = t-128;
        float s = lsq[0][c]+lsq[1][c]+lsq[2][c]+lsq[3][c];
        atomicAdd(&gsq[c], s);
    }
}

// ---------------- BN finalize + apply ----------------
__global__ void k_bnfin(const float* __restrict__ gsum, const float* __restrict__ gsq,
        const float* __restrict__ gamma, const float* __restrict__ beta,
        float* __restrict__ scale, float* __restrict__ shift, int n){
    int t = threadIdx.x;
    if (t < 128){
        float mu  = gsum[t]/(float)n;
        float var = gsq[t]/(float)n - mu*mu;
        float inv = rsqrtf(var + 1e-5f);
        float sc  = inv*gamma[t];
        scale[t] = sc;
        shift[t] = beta[t] - mu*sc;
    }
}

__global__ __launch_bounds__(256) void k_bnapply(float* __restrict__ out,
        const float* __restrict__ scale, const float* __restrict__ shift, long total4){
    __shared__ float sc[128], sh[128];
    if (threadIdx.x < 128){ sc[threadIdx.x]=scale[threadIdx.x]; sh[threadIdx.x]=shift[threadIdx.x]; }
    __syncthreads();
    long i = (long)blockIdx.x*blockDim.x + threadIdx.x;
    if (i < total4){
        float4* o4 = (float4*)out;
        float4 v = o4[i];
        int c = (int)((i & 31) * 4);
        v.x = v.x*sc[c+0]+sh[c+0];
        v.y = v.y*sc[c+1]+sh[c+1];
        v.z = v.z*sc[c+2]+sh[c+2];
        v.w = v.w*sc[c+3]+sh[c+3];
        o4[i]=v;
    }
}

extern "C" void kernel_launch(void* const* d_in, const int* in_sizes, int n_in,
                              void* d_out, int out_size, void* d_ws, size_t ws_size,
                              hipStream_t stream){
    const float* feats      = (const float*)d_in[0];
    const int* ei           = (const int*)d_in[1];   // harness converts int64 -> int32
    const float* Wsrc       = (const float*)d_in[2];
    const float* att_s      = (const float*)d_in[3];
    const float* att_d      = (const float*)d_in[4];
    const float* Wres       = (const float*)d_in[5];
    const float* bias       = (const float*)d_in[6];
    const float* gamma      = (const float*)d_in[7];
    const float* beta       = (const float*)d_in[8];
    int n = in_sizes[0]/128;
    int e = in_sizes[1]/2;
    float* out = (float*)d_out;

    char* w = (char*)d_ws;
    float* xp    = (float*)w; w += (size_t)n*128*4;
    float* a_src = (float*)w; w += (size_t)n*4*4;
    float* a_dst = (float*)w; w += (size_t)n*4*4;
    int*   deg   = (int*)w;   w += (size_t)n*4;
    int*   cursor= (int*)w;   w += (size_t)n*4;
    int*   offs  = (int*)w;   w += ((size_t)n+8)*4;
    int*   nbr   = (int*)w;   w += (size_t)e*4;
    int nb = (n+255)/256;
    int*   bsum  = (int*)w;   w += ((size_t)nb+8)*4;
    int*   boff  = (int*)w;   w += ((size_t)nb+8)*4;
    float* gsum  = (float*)w; w += 512;
    float* gsq   = (float*)w; w += 512;
    float* scale = (float*)w; w += 512;
    float* shift = (float*)w; w += 512;
    float* WTs   = (float*)w; w += 128*128*4;
    float* WTr   = (float*)w; w += 128*128*4;

    hipMemsetAsync(deg,    0, (size_t)n*4, stream);
    hipMemsetAsync(cursor, 0, (size_t)n*4, stream);
    hipMemsetAsync(gsum,   0, 512, stream);
    hipMemsetAsync(gsq,    0, 512, stream);

    k_transpose<<<dim3(64), 256, 0, stream>>>(Wsrc, Wres, WTs, WTr);
    k_gemm<<<dim3((n+63)/64), 256, 0, stream>>>(feats, WTs, WTr, xp, out, n);
    k_attn<<<dim3((n+3)/4), 256, 0, stream>>>(xp, att_s, att_d, a_src, a_dst, n);
    k_deg<<<dim3((e+255)/256), 256, 0, stream>>>(ei, deg, e);
    k_bsum<<<dim3(nb), 256, 0, stream>>>(deg, bsum, n);
    k_bscan<<<dim3(1), 64, 0, stream>>>(bsum, boff, nb);
    k_scan<<<dim3(nb), 256, 0, stream>>>(deg, boff, offs, n);
    k_scatter<<<dim3((e+255)/256), 256, 0, stream>>>(ei, offs, cursor, nbr, e);
    k_aggr<<<dim3((n+3)/4), 256, 0, stream>>>(xp, a_src, a_dst, offs, nbr, bias, out, gsum, gsq, n);
    k_bnfin<<<dim3(1), 128, 0, stream>>>(gsum, gsq, gamma, beta, scale, shift, n);
    long total4 = (long)n*32;
    k_bnapply<<<dim3((int)((total4+255)/256)), 256, 0, stream>>>(out, scale, shift, total4);
}